// Round 2
// baseline (2542.977 us; speedup 1.0000x reference)
//
#include <hip/hip_runtime.h>

typedef _Float16 f16;
typedef __attribute__((ext_vector_type(8))) _Float16 f16x8;
typedef __attribute__((ext_vector_type(4))) _Float16 f16x4;
typedef __attribute__((ext_vector_type(4))) float f32x4;

#define T_STEPS 784
#define HDIM    512
#define COUT    10

// One-time prep: W_rec f32 -> fp16 in frag-major layout.
// Frag (w, n, kk) = 64 lanes x 8 f16, contiguous 1 KB:
//   Wf[(((w*4+n)*16+kk)*64 + lane)*8 + j] = W_rec[w*64+n*16+(lane&15)][kk*32+(lane>>4)*8+j]
__global__ void cvt_w(const float* __restrict__ W, f16* __restrict__ Wf) {
    const int c  = blockIdx.x * 256 + threadIdx.x;   // 32768 chunks of 8 f16
    const int l  = c & 63;
    const int kk = (c >> 6) & 15;
    const int n  = (c >> 10) & 3;
    const int w  = c >> 12;
    const int row = w * 64 + n * 16 + (l & 15);
    const int col = kk * 32 + (l >> 4) * 8;
    const float* s = W + row * HDIM + col;
    f16* d = Wf + (size_t)c * 8;
#pragma unroll
    for (int j = 0; j < 8; ++j) d[j] = (f16)s[j];
}

// Persistent RNN: 64 WGs x 512 thr (8 waves, 2/SIMD). WG owns 16 batch rows.
// Roles swapped vs round 1: A operand = W rows (output cols), B operand = h rows.
//   D[outcol_sub, batch] : lane l, reg r -> outcol = lhi*4+r, batch = l&15
// W: k<256 resident in VGPRs (128/lane), k>=256 streamed from L2 each step
// (rolling 2-kk double buffers, issued early under the resident-MFMA phase).
// h in LDS fp16, double-buffered, XOR-swizzled: byte_off ^= (row&7)<<4
//   -> conflict-free ds_read_b128 and 8B ds_write_b64 epilogue stores.
__global__ __launch_bounds__(512, 2)
void rnn_main(const float* __restrict__ x, const float* __restrict__ W_in,
              const f16* __restrict__ Wf, const float* __restrict__ W_out,
              const float* __restrict__ b_out, const int* __restrict__ perm,
              float* __restrict__ out)
{
    __shared__ __align__(16) char hb[32768];   // 2 x (16 rows x 1024 B)
    const int tid  = threadIdx.x;
    const int w    = tid >> 6;
    const int lane = tid & 63;
    const int l15  = lane & 15;
    const int lhi  = lane >> 4;
    const int g    = l15 & 7;
    const int b0   = blockIdx.x * 16;

    for (int i = tid; i < 8192; i += 512) ((int*)hb)[i] = 0;

    // per-lane W frag base: frag (n,kk) at wb + (n*16+kk)*512
    const f16* wb = Wf + (size_t)w * 64 * 512 + lane * 8;

    // resident W frags: kk 0..7 (k < 256)
    f16x8 wr[32];
#pragma unroll
    for (int n = 0; n < 4; ++n)
#pragma unroll
        for (int kk = 0; kk < 8; ++kk)
            wr[n * 8 + kk] = *(const f16x8*)(wb + (n * 16 + kk) * 512);

    // W_in values for this lane's 16 output cols (4 per n-tile), packed f16
    f16x4 win[4];
#pragma unroll
    for (int n = 0; n < 4; ++n)
#pragma unroll
        for (int r = 0; r < 4; ++r)
            win[n][r] = (f16)W_in[w * 64 + n * 16 + lhi * 4 + r];

    // LDS read bases (swizzled): addr(kk) = (kk even ? Le : Lo) + kk*64
    const int P   = (lhi * 16) ^ ((g & 3) << 4);
    const int sw6 = (g & 4) ? 64 : 0;
    const int Le  = l15 * 1024 + P + sw6;
    const int Lo  = l15 * 1024 + P - sw6;
    // LDS write addrs (swizzled), one 8B store per n-tile
    int wA[4];
#pragma unroll
    for (int n = 0; n < 4; ++n)
        wA[n] = l15 * 1024 + ((w * 128 + lhi * 8 + n * 32) ^ (g << 4));

    const float* xp = x + (size_t)(b0 + l15) * T_STEPS;

    __syncthreads();

    int cur = 0;
#pragma unroll 2
    for (int t = 0; t < T_STEPS; ++t) {
        const int pt = perm[t];
        const float xv = xp[pt];

        const char* rp = hb + cur;

        // stream buffers: sA <- kk {8,9} issued at top
        f16x8 sA[8], sB[8];
#pragma unroll
        for (int n = 0; n < 4; ++n) {
            sA[n]     = *(const f16x8*)(wb + (n * 16 + 8) * 512);
            sA[4 + n] = *(const f16x8*)(wb + (n * 16 + 9) * 512);
        }

        f32x4 acc[4];
#pragma unroll
        for (int n = 0; n < 4; ++n) acc[n] = (f32x4){0.f, 0.f, 0.f, 0.f};

        // ---- resident phase: kk 0..7 ----
#pragma unroll
        for (int kk = 0; kk < 8; ++kk) {
            if (kk == 2) {
#pragma unroll
                for (int n = 0; n < 4; ++n) {
                    sB[n]     = *(const f16x8*)(wb + (n * 16 + 10) * 512);
                    sB[4 + n] = *(const f16x8*)(wb + (n * 16 + 11) * 512);
                }
            }
            const f16x8 bh = *(const f16x8*)(rp + ((kk & 1) ? Lo : Le) + kk * 64);
#pragma unroll
            for (int n = 0; n < 4; ++n)
                acc[n] = __builtin_amdgcn_mfma_f32_16x16x32_f16(wr[n * 8 + kk], bh, acc[n], 0, 0, 0);
        }

        // ---- streamed phase ----
#pragma unroll
        for (int kk = 8; kk < 10; ++kk) {
            const f16x8 bh = *(const f16x8*)(rp + ((kk & 1) ? Lo : Le) + kk * 64);
#pragma unroll
            for (int n = 0; n < 4; ++n)
                acc[n] = __builtin_amdgcn_mfma_f32_16x16x32_f16(sA[(kk - 8) * 4 + n], bh, acc[n], 0, 0, 0);
        }
#pragma unroll
        for (int n = 0; n < 4; ++n) {            // sA <- kk {12,13}
            sA[n]     = *(const f16x8*)(wb + (n * 16 + 12) * 512);
            sA[4 + n] = *(const f16x8*)(wb + (n * 16 + 13) * 512);
        }
#pragma unroll
        for (int kk = 10; kk < 12; ++kk) {
            const f16x8 bh = *(const f16x8*)(rp + ((kk & 1) ? Lo : Le) + kk * 64);
#pragma unroll
            for (int n = 0; n < 4; ++n)
                acc[n] = __builtin_amdgcn_mfma_f32_16x16x32_f16(sB[(kk - 10) * 4 + n], bh, acc[n], 0, 0, 0);
        }
#pragma unroll
        for (int n = 0; n < 4; ++n) {            // sB <- kk {14,15}
            sB[n]     = *(const f16x8*)(wb + (n * 16 + 14) * 512);
            sB[4 + n] = *(const f16x8*)(wb + (n * 16 + 15) * 512);
        }
#pragma unroll
        for (int kk = 12; kk < 14; ++kk) {
            const f16x8 bh = *(const f16x8*)(rp + ((kk & 1) ? Lo : Le) + kk * 64);
#pragma unroll
            for (int n = 0; n < 4; ++n)
                acc[n] = __builtin_amdgcn_mfma_f32_16x16x32_f16(sA[(kk - 12) * 4 + n], bh, acc[n], 0, 0, 0);
        }
#pragma unroll
        for (int kk = 14; kk < 16; ++kk) {
            const f16x8 bh = *(const f16x8*)(rp + ((kk & 1) ? Lo : Le) + kk * 64);
#pragma unroll
            for (int n = 0; n < 4; ++n)
                acc[n] = __builtin_amdgcn_mfma_f32_16x16x32_f16(sB[(kk - 14) * 4 + n], bh, acc[n], 0, 0, 0);
        }

        // ---- epilogue: inject + relu, packed 8B stores ----
        char* wp_ = hb + (cur ^ 16384);
#pragma unroll
        for (int n = 0; n < 4; ++n) {
            f16x4 hv;
#pragma unroll
            for (int r = 0; r < 4; ++r) {
                float v = acc[n][r] + xv * (float)win[n][r];
                hv[r] = (f16)fmaxf(v, 0.f);
            }
            *(f16x4*)(wp_ + wA[n]) = hv;
        }
        __syncthreads();
        cur ^= 16384;
    }

    // final projection: out[b, c] = h_last[b,:] . W_out[c,:] + b_out[c]
    if (tid < 16 * COUT) {
        const int r = tid / COUT, c = tid % COUT;
        const char* hr = hb + cur + r * 1024;
        const int gr = (r & 7) << 4;
        float s_ = b_out[c];
        const float* wo = W_out + c * HDIM;
#pragma unroll 4
        for (int j0 = 0; j0 < HDIM; j0 += 8) {
            f16x8 hv = *(const f16x8*)(hr + ((j0 * 2) ^ gr));
#pragma unroll
            for (int jj = 0; jj < 8; ++jj)
                s_ += (float)hv[jj] * wo[j0 + jj];
        }
        out[(b0 + r) * COUT + c] = s_;
    }
}

extern "C" void kernel_launch(void* const* d_in, const int* in_sizes, int n_in,
                              void* d_out, int out_size, void* d_ws, size_t ws_size,
                              hipStream_t stream)
{
    (void)in_sizes; (void)n_in; (void)out_size; (void)ws_size;
    const float* x     = (const float*)d_in[0];
    const float* W_in  = (const float*)d_in[1];
    const float* W_rec = (const float*)d_in[2];
    const float* W_out = (const float*)d_in[3];
    const float* b_out = (const float*)d_in[4];
    const int*   perm  = (const int*)d_in[5];
    float* out = (float*)d_out;
    f16* Wf = (f16*)d_ws;   // 512 KB

    cvt_w<<<dim3(128), dim3(256), 0, stream>>>(W_rec, Wf);
    rnn_main<<<dim3(64), dim3(512), 0, stream>>>(x, W_in, Wf, W_out, b_out, perm, out);
}